// Round 1
// baseline (67.838 us; speedup 1.0000x reference)
//
#include <hip/hip_runtime.h>
#include <math.h>

#define N_ROWS 8192
#define D 16
#define TILE 128
#define NT 64            /* 8192/128 */

/* workspace layout (bytes) */
#define OFF_PT   0        /* float pt[4096]   */
#define OFF_PS   16384    /* float ps[4096]   */
#define OFF_CNT  32768    /* int   cnt[8]     */
#define OFF_SQ   33280    /* float sq[8192]   */
#define OFF_FA   66048    /* float fa[8192]   */
#define OFF_FB   98816    /* float fb[8192]   */

#if __has_builtin(__builtin_amdgcn_sqrtf)
#define SQRTF(x) __builtin_amdgcn_sqrtf(x)
#else
#define SQRTF(x) sqrtf(x)
#endif

/* codon index -> biosynthetic family id (K resolves to aspartate; '*' -> -1)
   families: 0=glutamate 1=aspartate 2=serine 3=pyruvate 4=aromatic 5=histidine */
__device__ __constant__ signed char FAM_LUT[64] = {
  4,4,3,3, 3,3,3,3,   /* UUU..CUG: F F L L L L L L */
  1,1,1,1, 3,3,3,3,   /* AUU..GUG: I I I M V V V V */
  2,2,2,2, 0,0,0,0,   /* UCU..CCG: S S S S P P P P */
  1,1,1,1, 3,3,3,3,   /* ACU..GCG: T T T T A A A A */
  4,4,-1,-1, 5,5,0,0, /* UAU..CAG: Y Y * * H H Q Q */
  1,1,1,1, 1,1,0,0,   /* AAU..GAG: N N K K D D E E */
  2,2,-1,4, 0,0,0,0,  /* UGU..CGG: C C * W R R R R */
  2,2,0,0, 2,2,2,2    /* AGU..GGG: S S R R G G G G */
};

__device__ __forceinline__ float dot16(const float* a, const float* b) {
  float s = a[0] * b[0];
#pragma unroll
  for (int k = 1; k < 16; ++k) s = fmaf(a[k], b[k], s);
  return s;
}

__device__ __forceinline__ void unpack4(float* dst, float4 a0, float4 a1, float4 a2, float4 a3) {
  dst[0]=a0.x;  dst[1]=a0.y;  dst[2]=a0.z;  dst[3]=a0.w;
  dst[4]=a1.x;  dst[5]=a1.y;  dst[6]=a1.z;  dst[7]=a1.w;
  dst[8]=a2.x;  dst[9]=a2.y;  dst[10]=a2.z; dst[11]=a2.w;
  dst[12]=a3.x; dst[13]=a3.y; dst[14]=a3.z; dst[15]=a3.w;
}

__global__ __launch_bounds__(256) void prep_kernel(
    const float* __restrict__ emb, const int* __restrict__ idx,
    float* __restrict__ sq, float* __restrict__ fa, float* __restrict__ fb,
    int* __restrict__ cnt) {
  __shared__ int hist[8];
  const int t = threadIdx.x;
  if (t < 8) hist[t] = 0;
  __syncthreads();

  const int i = blockIdx.x * 256 + t;
  const float4* src = (const float4*)(emb + (size_t)i * D);
  float v[16];
  unpack4(v, src[0], src[1], src[2], src[3]);
  sq[i] = dot16(v, v);   /* same FMA chain as pair kernel -> exact diagonal zero */

  const int f = FAM_LUT[idx[i] & 63];
  fa[i] = (f >= 0) ? (float)f : -1.0f;  /* i-side: None = -1 */
  fb[i] = (f >= 0) ? (float)f : -2.0f;  /* j-side: None = -2 (so None != None) */
  if (f >= 0) atomicAdd(&hist[f], 1);
  __syncthreads();
  if (t < 8) atomicAdd(&cnt[t], hist[t]);
}

__global__ __launch_bounds__(256, 2) void pair_kernel(
    const float* __restrict__ emb, const float* __restrict__ sq,
    const float* __restrict__ fa, const float* __restrict__ fb,
    float* __restrict__ pt, float* __restrict__ ps) {
  const int it = blockIdx.y, jt = blockIdx.x;
  if (jt < it) return;  /* lower triangle skipped; partials pre-zeroed by memset */

  __shared__ float4 Bj[TILE * 4];   /* 128 rows x 16 floats */
  __shared__ float2 SF[TILE];       /* x = sq_j, y = famB_j */
  __shared__ float  rT[4], rS[4];

  const int t = threadIdx.x;
  /* stage j-tile: each thread loads half a row (2x float4, coalesced) */
  {
    const int r = t >> 1, h = t & 1;
    const float4* src = (const float4*)(emb + (size_t)(jt * TILE + r) * D);
    Bj[r * 4 + h * 2 + 0] = src[h * 2 + 0];
    Bj[r * 4 + h * 2 + 1] = src[h * 2 + 1];
    if (t < TILE) SF[t] = make_float2(sq[jt * TILE + t], fb[jt * TILE + t]);
  }
  __syncthreads();

  const int ti = t & 15;   /* 16 i-groups x 8 rows = 128 */
  const int tj = t >> 4;   /* 16 j-groups x 8 cols = 128 */
  const int i0 = it * TILE + ti * 8;

  float ai[8][16], sqi[8], fai[8];
#pragma unroll
  for (int r = 0; r < 8; ++r) {
    const float4* src = (const float4*)(emb + (size_t)(i0 + r) * D);
    unpack4(ai[r], src[0], src[1], src[2], src[3]);
    sqi[r] = sq[i0 + r];
    fai[r] = fa[i0 + r];
  }

  float accT = 0.0f, accS = 0.0f;
#pragma unroll
  for (int jj = 0; jj < 8; ++jj) {
    const int j = tj * 8 + jj;
    float bj[16];
    unpack4(bj, Bj[j * 4 + 0], Bj[j * 4 + 1], Bj[j * 4 + 2], Bj[j * 4 + 3]);
    const float2 sf = SF[j];
#pragma unroll
    for (int r = 0; r < 8; ++r) {
      const float dp = dot16(ai[r], bj);
      float d2 = fmaf(-2.0f, dp, sqi[r] + sf.x);
      d2 = fmaxf(d2, 0.0f);
      const float dist = SQRTF(d2);   /* sqrt(0)==0 covers the mask */
      accT += dist;
      accS += (fai[r] == sf.y) ? dist : 0.0f;
    }
  }

  /* block reduction (fp32 partials are ~1e5, exact enough) */
#pragma unroll
  for (int off = 32; off > 0; off >>= 1) {
    accT += __shfl_down(accT, off);
    accS += __shfl_down(accS, off);
  }
  if ((t & 63) == 0) { rT[t >> 6] = accT; rS[t >> 6] = accS; }
  __syncthreads();
  if (t == 0) {
    const float w = (it == jt) ? 1.0f : 2.0f;
    const int bid = it * NT + jt;
    pt[bid] = w * (rT[0] + rT[1] + rT[2] + rT[3]);
    ps[bid] = w * (rS[0] + rS[1] + rS[2] + rS[3]);
  }
}

__global__ __launch_bounds__(256) void final_kernel(
    const float* __restrict__ pt, const float* __restrict__ ps,
    const int* __restrict__ cnt, float* __restrict__ out) {
  const int t = threadIdx.x;
  double sT = 0.0, sS = 0.0;
  for (int k = t; k < NT * NT; k += 256) { sT += (double)pt[k]; sS += (double)ps[k]; }
#pragma unroll
  for (int off = 32; off > 0; off >>= 1) {
    sT += __shfl_down(sT, off);
    sS += __shfl_down(sS, off);
  }
  __shared__ double rT[4], rS[4];
  if ((t & 63) == 0) { rT[t >> 6] = sT; rS[t >> 6] = sS; }
  __syncthreads();
  if (t == 0) {
    const double tot = rT[0] + rT[1] + rT[2] + rT[3];
    const double sam = rS[0] + rS[1] + rS[2] + rS[3];
    double same_sum = 0.0;
    for (int f = 0; f < 6; ++f) { const double c = (double)cnt[f]; same_sum += c * c; }
    const double total  = (double)N_ROWS * (double)N_ROWS;
    const double same_d = sam / (same_sum + 1e-10);
    const double diff_d = (tot - sam) / (total - same_sum + 1e-10);
    double loss = same_d - 0.5 * diff_d + 1.0;
    out[0] = (float)(loss > 0.0 ? loss : 0.0);
  }
}

extern "C" void kernel_launch(void* const* d_in, const int* in_sizes, int n_in,
                              void* d_out, int out_size, void* d_ws, size_t ws_size,
                              hipStream_t stream) {
  const float* emb = (const float*)d_in[0];
  const int*   idx = (const int*)d_in[1];
  char* ws = (char*)d_ws;
  float* pt  = (float*)(ws + OFF_PT);
  float* ps  = (float*)(ws + OFF_PS);
  int*   cnt = (int*)(ws + OFF_CNT);
  float* sqv = (float*)(ws + OFF_SQ);
  float* fav = (float*)(ws + OFF_FA);
  float* fbv = (float*)(ws + OFF_FB);

  /* zero partials + histogram (pt, ps, cnt) */
  hipMemsetAsync(d_ws, 0, OFF_SQ, stream);
  prep_kernel<<<dim3(N_ROWS / 256), dim3(256), 0, stream>>>(emb, idx, sqv, fav, fbv, cnt);
  pair_kernel<<<dim3(NT, NT), dim3(256), 0, stream>>>(emb, sqv, fav, fbv, pt, ps);
  final_kernel<<<dim3(1), dim3(256), 0, stream>>>(pt, ps, cnt, (float*)d_out);
}

// Round 2
// 40.303 us; speedup vs baseline: 1.6832x; 1.6832x over previous
//
#include <hip/hip_runtime.h>
#include <math.h>

#define N_ROWS 8192
#define D 16
#define TILE 128
#define NT 64            /* 8192/128 */
#define NBLK 2080        /* NT*(NT+1)/2 upper-tri tiles */

/* workspace layout (bytes) */
#define OFF_PT   0        /* float pt[2080]   */
#define OFF_PS   16384    /* float ps[2080]   */
#define OFF_CNT  32768    /* int   cnt[8]     */
#define OFF_SQ   33280    /* float sq[8192]   */
#define OFF_FA   66048    /* float fa[8192]   */
#define OFF_FB   98816    /* float fb[8192]   */

#if __has_builtin(__builtin_amdgcn_sqrtf)
#define SQRTF(x) __builtin_amdgcn_sqrtf(x)
#else
#define SQRTF(x) sqrtf(x)
#endif

/* codon index -> biosynthetic family id (K resolves to aspartate; '*' -> -1)
   families: 0=glutamate 1=aspartate 2=serine 3=pyruvate 4=aromatic 5=histidine */
__device__ __constant__ signed char FAM_LUT[64] = {
  4,4,3,3, 3,3,3,3,   /* UUU..CUG: F F L L L L L L */
  1,1,1,1, 3,3,3,3,   /* AUU..GUG: I I I M V V V V */
  2,2,2,2, 0,0,0,0,   /* UCU..CCG: S S S S P P P P */
  1,1,1,1, 3,3,3,3,   /* ACU..GCG: T T T T A A A A */
  4,4,-1,-1, 5,5,0,0, /* UAU..CAG: Y Y * * H H Q Q */
  1,1,1,1, 1,1,0,0,   /* AAU..GAG: N N K K D D E E */
  2,2,-1,4, 0,0,0,0,  /* UGU..CGG: C C * W R R R R */
  2,2,0,0, 2,2,2,2    /* AGU..GGG: S S R R G G G G */
};

__device__ __forceinline__ float dot16(const float* a, const float* b) {
  float s = a[0] * b[0];
#pragma unroll
  for (int k = 1; k < 16; ++k) s = fmaf(a[k], b[k], s);
  return s;
}

__device__ __forceinline__ void unpack4(float* dst, float4 a0, float4 a1, float4 a2, float4 a3) {
  dst[0]=a0.x;  dst[1]=a0.y;  dst[2]=a0.z;  dst[3]=a0.w;
  dst[4]=a1.x;  dst[5]=a1.y;  dst[6]=a1.z;  dst[7]=a1.w;
  dst[8]=a2.x;  dst[9]=a2.y;  dst[10]=a2.z; dst[11]=a2.w;
  dst[12]=a3.x; dst[13]=a3.y; dst[14]=a3.z; dst[15]=a3.w;
}

__global__ __launch_bounds__(256) void prep_kernel(
    const float* __restrict__ emb, const int* __restrict__ idx,
    float* __restrict__ sq, float* __restrict__ fa, float* __restrict__ fb,
    int* __restrict__ cnt) {
  __shared__ int hist[8];
  const int t = threadIdx.x;
  if (t < 8) hist[t] = 0;
  __syncthreads();

  const int i = blockIdx.x * 256 + t;
  const float4* src = (const float4*)(emb + (size_t)i * D);
  float v[16];
  unpack4(v, src[0], src[1], src[2], src[3]);
  sq[i] = dot16(v, v);   /* same FMA chain as pair kernel -> exact diagonal zero */

  const int f = FAM_LUT[idx[i] & 63];
  fa[i] = (f >= 0) ? (float)f : -1.0f;  /* i-side: None = -1 */
  fb[i] = (f >= 0) ? (float)f : -2.0f;  /* j-side: None = -2 (so None != None) */
  if (f >= 0) atomicAdd(&hist[f], 1);
  __syncthreads();
  if (t < 8) atomicAdd(&cnt[t], hist[t]);
}

__global__ __launch_bounds__(256, 4) void pair_kernel(
    const float* __restrict__ emb, const float* __restrict__ sq,
    const float* __restrict__ fa, const float* __restrict__ fb,
    float* __restrict__ pt, float* __restrict__ ps) {
  /* triangular fold: grid (65, 32) -> every block is a live upper-tri tile */
  const int u = blockIdx.y, bx = blockIdx.x;
  int it, jt;
  if (bx < NT - u) { it = u;          jt = u + bx; }
  else             { it = NT - 1 - u; jt = bx - 1; }

  __shared__ float4 Bj[TILE * 4];   /* 128 rows x 16 floats */
  __shared__ float2 SF[TILE];       /* x = sq_j, y = famB_j */
  __shared__ float  rT[4], rS[4];

  const int t = threadIdx.x;
  /* stage j-tile: each thread loads half a row (2x float4, coalesced) */
  {
    const int r = t >> 1, h = t & 1;
    const float4* src = (const float4*)(emb + (size_t)(jt * TILE + r) * D);
    Bj[r * 4 + h * 2 + 0] = src[h * 2 + 0];
    Bj[r * 4 + h * 2 + 1] = src[h * 2 + 1];
    if (t < TILE) SF[t] = make_float2(sq[jt * TILE + t], fb[jt * TILE + t]);
  }

  const int ti = t & 31;   /* 32 i-groups x 4 rows = 128 */
  const int tj = t >> 5;   /*  8 j-groups x 16 cols = 128 */
  const int i0 = it * TILE + ti * 4;

  float ai[4][16], sqi[4], fai[4];
#pragma unroll
  for (int r = 0; r < 4; ++r) {
    const float4* src = (const float4*)(emb + (size_t)(i0 + r) * D);
    unpack4(ai[r], src[0], src[1], src[2], src[3]);
    sqi[r] = sq[i0 + r];
    fai[r] = fa[i0 + r];
  }
  __syncthreads();

  float accT = 0.0f, accS = 0.0f;
#pragma unroll
  for (int jj = 0; jj < 16; ++jj) {
    const int j = tj * 16 + jj;
    float bj[16];
    unpack4(bj, Bj[j * 4 + 0], Bj[j * 4 + 1], Bj[j * 4 + 2], Bj[j * 4 + 3]);
    const float2 sf = SF[j];
#pragma unroll
    for (int r = 0; r < 4; ++r) {
      const float dp = dot16(ai[r], bj);
      float d2 = fmaf(-2.0f, dp, sqi[r] + sf.x);
      d2 = fmaxf(d2, 0.0f);
      const float dist = SQRTF(d2);   /* sqrt(0)==0 covers the mask */
      accT += dist;
      accS += (fai[r] == sf.y) ? dist : 0.0f;
    }
  }

  /* block reduction (fp32 partials are ~1e5, exact enough) */
#pragma unroll
  for (int off = 32; off > 0; off >>= 1) {
    accT += __shfl_down(accT, off);
    accS += __shfl_down(accS, off);
  }
  if ((t & 63) == 0) { rT[t >> 6] = accT; rS[t >> 6] = accS; }
  __syncthreads();
  if (t == 0) {
    const float w = (it == jt) ? 1.0f : 2.0f;
    const int bid = blockIdx.y * gridDim.x + blockIdx.x;
    pt[bid] = w * (rT[0] + rT[1] + rT[2] + rT[3]);
    ps[bid] = w * (rS[0] + rS[1] + rS[2] + rS[3]);
  }
}

__global__ __launch_bounds__(256) void final_kernel(
    const float* __restrict__ pt, const float* __restrict__ ps,
    const int* __restrict__ cnt, float* __restrict__ out) {
  const int t = threadIdx.x;
  double sT = 0.0, sS = 0.0;
  for (int k = t; k < NBLK; k += 256) { sT += (double)pt[k]; sS += (double)ps[k]; }
#pragma unroll
  for (int off = 32; off > 0; off >>= 1) {
    sT += __shfl_down(sT, off);
    sS += __shfl_down(sS, off);
  }
  __shared__ double rT[4], rS[4];
  if ((t & 63) == 0) { rT[t >> 6] = sT; rS[t >> 6] = sS; }
  __syncthreads();
  if (t == 0) {
    const double tot = rT[0] + rT[1] + rT[2] + rT[3];
    const double sam = rS[0] + rS[1] + rS[2] + rS[3];
    double same_sum = 0.0;
    for (int f = 0; f < 6; ++f) { const double c = (double)cnt[f]; same_sum += c * c; }
    const double total  = (double)N_ROWS * (double)N_ROWS;
    const double same_d = sam / (same_sum + 1e-10);
    const double diff_d = (tot - sam) / (total - same_sum + 1e-10);
    double loss = same_d - 0.5 * diff_d + 1.0;
    out[0] = (float)(loss > 0.0 ? loss : 0.0);
  }
}

extern "C" void kernel_launch(void* const* d_in, const int* in_sizes, int n_in,
                              void* d_out, int out_size, void* d_ws, size_t ws_size,
                              hipStream_t stream) {
  const float* emb = (const float*)d_in[0];
  const int*   idx = (const int*)d_in[1];
  char* ws = (char*)d_ws;
  float* pt  = (float*)(ws + OFF_PT);
  float* ps  = (float*)(ws + OFF_PS);
  int*   cnt = (int*)(ws + OFF_CNT);
  float* sqv = (float*)(ws + OFF_SQ);
  float* fav = (float*)(ws + OFF_FA);
  float* fbv = (float*)(ws + OFF_FB);

  /* zero only the family histogram (every pt/ps slot is written by its block) */
  hipMemsetAsync(cnt, 0, 8 * sizeof(int), stream);
  prep_kernel<<<dim3(N_ROWS / 256), dim3(256), 0, stream>>>(emb, idx, sqv, fav, fbv, cnt);
  pair_kernel<<<dim3(NT + 1, NT / 2), dim3(256), 0, stream>>>(emb, sqv, fav, fbv, pt, ps);
  final_kernel<<<dim3(1), dim3(256), 0, stream>>>(pt, ps, cnt, (float*)d_out);
}

// Round 3
// 32.414 us; speedup vs baseline: 2.0929x; 1.2434x over previous
//
#include <hip/hip_runtime.h>
#include <math.h>

#define N_ROWS 8192
#define D 16
#define TILE 128
#define NT 64            /* 8192/128 */
#define NBLK 2080        /* NT*(NT+1)/2 upper-tri tiles */

/* workspace layout (bytes) */
#define OFF_PT   0            /* float  pt[2080] */
#define OFF_PS   16384        /* float  ps[2080] */
#define OFF_SQ   32768        /* float  sq[8192] */
#define OFF_FA   65536        /* float  fa[8192] */
#define OFF_FB   98304        /* float  fb[8192] */
#define OFF_EHI  131072       /* ushort ehi[8192*16] (256KB) */
#define OFF_ELO  393216       /* ushort elo[8192*16] (256KB) */

typedef short  bf16x8 __attribute__((ext_vector_type(8)));
typedef float  f32x4  __attribute__((ext_vector_type(4)));

#if __has_builtin(__builtin_amdgcn_sqrtf)
#define SQRTF(x) __builtin_amdgcn_sqrtf(x)
#else
#define SQRTF(x) sqrtf(x)
#endif

/* codon index -> biosynthetic family id (K resolves to aspartate; '*' -> -1)
   families: 0=glutamate 1=aspartate 2=serine 3=pyruvate 4=aromatic 5=histidine */
__device__ __constant__ signed char FAM_LUT[64] = {
  4,4,3,3, 3,3,3,3,   /* UUU..CUG: F F L L L L L L */
  1,1,1,1, 3,3,3,3,   /* AUU..GUG: I I I M V V V V */
  2,2,2,2, 0,0,0,0,   /* UCU..CCG: S S S S P P P P */
  1,1,1,1, 3,3,3,3,   /* ACU..GCG: T T T T A A A A */
  4,4,-1,-1, 5,5,0,0, /* UAU..CAG: Y Y * * H H Q Q */
  1,1,1,1, 1,1,0,0,   /* AAU..GAG: N N K K D D E E */
  2,2,-1,4, 0,0,0,0,  /* UGU..CGG: C C * W R R R R */
  2,2,0,0, 2,2,2,2    /* AGU..GGG: S S R R G G G G */
};

__device__ __forceinline__ unsigned short f2bf(float f) {   /* RNE, finite inputs */
  unsigned u = __float_as_uint(f);
  u += 0x7fffu + ((u >> 16) & 1u);
  return (unsigned short)(u >> 16);
}
__device__ __forceinline__ float bf2f(unsigned short s) {
  return __uint_as_float((unsigned)s << 16);
}

/* prep: per-row |e|^2, family floats, and the global bf16 hi/lo split */
__global__ __launch_bounds__(256) void prep_kernel(
    const float* __restrict__ emb, const int* __restrict__ idx,
    float* __restrict__ sq, float* __restrict__ fa, float* __restrict__ fb,
    unsigned short* __restrict__ ehi, unsigned short* __restrict__ elo) {
  const int i = blockIdx.x * 256 + threadIdx.x;
  const float4* src = (const float4*)(emb + (size_t)i * D);
  float v[16];
  float4 a0 = src[0], a1 = src[1], a2 = src[2], a3 = src[3];
  v[0]=a0.x; v[1]=a0.y; v[2]=a0.z; v[3]=a0.w;
  v[4]=a1.x; v[5]=a1.y; v[6]=a1.z; v[7]=a1.w;
  v[8]=a2.x; v[9]=a2.y; v[10]=a2.z; v[11]=a2.w;
  v[12]=a3.x; v[13]=a3.y; v[14]=a3.z; v[15]=a3.w;

  float s = v[0] * v[0];
  unsigned short hi[16], lo[16];
#pragma unroll
  for (int k = 0; k < 16; ++k) {
    if (k) s = fmaf(v[k], v[k], s);
    hi[k] = f2bf(v[k]);
    lo[k] = f2bf(v[k] - bf2f(hi[k]));
  }
  sq[i] = s;
  {
    bf16x8* dh = (bf16x8*)(ehi + (size_t)i * 16);
    bf16x8* dl = (bf16x8*)(elo + (size_t)i * 16);
    dh[0] = *(bf16x8*)&hi[0]; dh[1] = *(bf16x8*)&hi[8];
    dl[0] = *(bf16x8*)&lo[0]; dl[1] = *(bf16x8*)&lo[8];
  }
  const int f = FAM_LUT[idx[i] & 63];
  fa[i] = (f >= 0) ? (float)f : -1.0f;  /* i-side: None = -1 */
  fb[i] = (f >= 0) ? (float)f : -2.0f;  /* j-side: None = -2 (None != None) */
}

__global__ __launch_bounds__(256, 4) void pair_kernel(
    const unsigned short* __restrict__ ehi, const unsigned short* __restrict__ elo,
    const float* __restrict__ sq,
    const float* __restrict__ fa, const float* __restrict__ fb,
    float* __restrict__ pt, float* __restrict__ ps) {
  /* triangular fold: grid (65,32) -> every block a live upper-tri 128x128 tile */
  const int u = blockIdx.y, bx = blockIdx.x;
  int it, jt;
  if (bx < NT - u) { it = u;          jt = u + bx; }
  else             { it = NT - 1 - u; jt = bx - 1; }

  const int t  = threadIdx.x;
  const int w  = t >> 6;          /* wave 0..3: owns i-strips 2w, 2w+1 */
  const int l  = t & 63;
  const int lr = l & 15;          /* A/B fragment row index */
  const int g  = l >> 4;          /* k-slice group 0..3 */
  const int half = g & 1;         /* dims 0-7 vs 8-15 */

  /* A fragments: pack1 = [hi | lo] along K=32 -> group g<2 takes hi, g>=2 lo */
  const unsigned short* asrc = (g < 2) ? ehi : elo;
  bf16x8 afrag[2];
  float sqi[2][4], fai[2][4];
#pragma unroll
  for (int s = 0; s < 2; ++s) {
    const int arow = it * TILE + (w * 2 + s) * 16 + lr;
    afrag[s] = *(const bf16x8*)(asrc + (size_t)arow * 16 + half * 8);
#pragma unroll
    for (int r = 0; r < 4; ++r) {
      const int irow = it * TILE + (w * 2 + s) * 16 + g * 4 + r;  /* C/D row = g*4+r */
      sqi[s][r] = sq[irow];
      fai[s][r] = fa[irow];
    }
  }

  float accT = 0.0f, accS = 0.0f;
#pragma unroll 4
  for (int mj = 0; mj < 8; ++mj) {
    const int jrow = jt * TILE + mj * 16 + lr;
    const bf16x8 bhi = *(const bf16x8*)(ehi + (size_t)jrow * 16 + half * 8);
    const bf16x8 blo = *(const bf16x8*)(elo + (size_t)jrow * 16 + half * 8);
    const float sqj = sq[jrow];        /* C/D col = lr */
    const float faj = fb[jrow];
#pragma unroll
    for (int s = 0; s < 2; ++s) {
      /* B = hi replicated along K gives (hi_a+lo_a)*hi_b; B = lo gives *lo_b */
      f32x4 acc = {0.0f, 0.0f, 0.0f, 0.0f};
      acc = __builtin_amdgcn_mfma_f32_16x16x32_bf16(afrag[s], blo, acc, 0, 0, 0);
      acc = __builtin_amdgcn_mfma_f32_16x16x32_bf16(afrag[s], bhi, acc, 0, 0, 0);
#pragma unroll
      for (int r = 0; r < 4; ++r) {
        float d2 = fmaf(-2.0f, acc[r], sqi[s][r] + sqj);
        d2 = fmaxf(d2, 0.0f);
        const float dist = SQRTF(d2);
        accT += dist;
        accS += (fai[s][r] == faj) ? dist : 0.0f;
      }
    }
  }

  /* block reduction (fp32 partials ~1e5, fine) */
#pragma unroll
  for (int off = 32; off > 0; off >>= 1) {
    accT += __shfl_down(accT, off);
    accS += __shfl_down(accS, off);
  }
  __shared__ float rT[4], rS[4];
  if ((t & 63) == 0) { rT[w] = accT; rS[w] = accS; }
  __syncthreads();
  if (t == 0) {
    const float wgt = (it == jt) ? 1.0f : 2.0f;
    const int bid = blockIdx.y * gridDim.x + blockIdx.x;
    pt[bid] = wgt * (rT[0] + rT[1] + rT[2] + rT[3]);
    ps[bid] = wgt * (rS[0] + rS[1] + rS[2] + rS[3]);
  }
}

__global__ __launch_bounds__(256) void final_kernel(
    const float* __restrict__ pt, const float* __restrict__ ps,
    const int* __restrict__ idx, float* __restrict__ out) {
  const int t = threadIdx.x;
  __shared__ int hist[8];
  if (t < 8) hist[t] = 0;
  __syncthreads();
  for (int k = t; k < N_ROWS; k += 256) {
    const int f = FAM_LUT[idx[k] & 63];
    if (f >= 0) atomicAdd(&hist[f], 1);
  }

  double sT = 0.0, sS = 0.0;
  for (int k = t; k < NBLK; k += 256) { sT += (double)pt[k]; sS += (double)ps[k]; }
#pragma unroll
  for (int off = 32; off > 0; off >>= 1) {
    sT += __shfl_down(sT, off);
    sS += __shfl_down(sS, off);
  }
  __shared__ double rT[4], rS[4];
  if ((t & 63) == 0) { rT[t >> 6] = sT; rS[t >> 6] = sS; }
  __syncthreads();
  if (t == 0) {
    const double tot = rT[0] + rT[1] + rT[2] + rT[3];
    const double sam = rS[0] + rS[1] + rS[2] + rS[3];
    double same_sum = 0.0;
    for (int f = 0; f < 6; ++f) { const double c = (double)hist[f]; same_sum += c * c; }
    const double total  = (double)N_ROWS * (double)N_ROWS;
    const double same_d = sam / (same_sum + 1e-10);
    const double diff_d = (tot - sam) / (total - same_sum + 1e-10);
    double loss = same_d - 0.5 * diff_d + 1.0;
    out[0] = (float)(loss > 0.0 ? loss : 0.0);
  }
}

extern "C" void kernel_launch(void* const* d_in, const int* in_sizes, int n_in,
                              void* d_out, int out_size, void* d_ws, size_t ws_size,
                              hipStream_t stream) {
  const float* emb = (const float*)d_in[0];
  const int*   idx = (const int*)d_in[1];
  char* ws = (char*)d_ws;
  float*          pt  = (float*)(ws + OFF_PT);
  float*          ps  = (float*)(ws + OFF_PS);
  float*          sqv = (float*)(ws + OFF_SQ);
  float*          fav = (float*)(ws + OFF_FA);
  float*          fbv = (float*)(ws + OFF_FB);
  unsigned short* ehi = (unsigned short*)(ws + OFF_EHI);
  unsigned short* elo = (unsigned short*)(ws + OFF_ELO);

  prep_kernel<<<dim3(N_ROWS / 256), dim3(256), 0, stream>>>(emb, idx, sqv, fav, fbv, ehi, elo);
  pair_kernel<<<dim3(NT + 1, NT / 2), dim3(256), 0, stream>>>(ehi, elo, sqv, fav, fbv, pt, ps);
  final_kernel<<<dim3(1), dim3(256), 0, stream>>>(pt, ps, idx, (float*)d_out);
}

// Round 4
// 27.443 us; speedup vs baseline: 2.4719x; 1.1811x over previous
//
#include <hip/hip_runtime.h>
#include <math.h>

#define N_ROWS 8192
#define D 16
#define TILE 128
#define NT 64            /* 8192/128 */
#define NBLK 2080        /* NT*(NT+1)/2 upper-tri tiles */

/* workspace layout (bytes) */
#define OFF_PT   0            /* float  pt[2080] */
#define OFF_PS   16384        /* float  ps[2080] */
#define OFF_SQ   32768        /* float  sq[8192] */
#define OFF_FA   65536        /* float  fa[8192] */
#define OFF_FB   98304        /* float  fb[8192] */
#define OFF_EHI  131072       /* ushort ehi[8192*16] (256KB) */
#define OFF_ELO  393216       /* ushort elo[8192*16] (256KB) */

typedef short  bf16x8 __attribute__((ext_vector_type(8)));
typedef float  f32x4  __attribute__((ext_vector_type(4)));

#if __has_builtin(__builtin_amdgcn_sqrtf)
#define SQRTF(x) __builtin_amdgcn_sqrtf(x)
#else
#define SQRTF(x) sqrtf(x)
#endif

/* codon index -> biosynthetic family id (K resolves to aspartate; '*' -> -1)
   families: 0=glutamate 1=aspartate 2=serine 3=pyruvate 4=aromatic 5=histidine */
__device__ __constant__ signed char FAM_LUT[64] = {
  4,4,3,3, 3,3,3,3,   /* UUU..CUG: F F L L L L L L */
  1,1,1,1, 3,3,3,3,   /* AUU..GUG: I I I M V V V V */
  2,2,2,2, 0,0,0,0,   /* UCU..CCG: S S S S P P P P */
  1,1,1,1, 3,3,3,3,   /* ACU..GCG: T T T T A A A A */
  4,4,-1,-1, 5,5,0,0, /* UAU..CAG: Y Y * * H H Q Q */
  1,1,1,1, 1,1,0,0,   /* AAU..GAG: N N K K D D E E */
  2,2,-1,4, 0,0,0,0,  /* UGU..CGG: C C * W R R R R */
  2,2,0,0, 2,2,2,2    /* AGU..GGG: S S R R G G G G */
};

__device__ __forceinline__ unsigned short f2bf(float f) {   /* RNE, finite inputs */
  unsigned u = __float_as_uint(f);
  u += 0x7fffu + ((u >> 16) & 1u);
  return (unsigned short)(u >> 16);
}
__device__ __forceinline__ float bf2f(unsigned short s) {
  return __uint_as_float((unsigned)s << 16);
}

/* prep: per-row |e|^2, family floats, and the global bf16 hi/lo split */
__global__ __launch_bounds__(256) void prep_kernel(
    const float* __restrict__ emb, const int* __restrict__ idx,
    float* __restrict__ sq, float* __restrict__ fa, float* __restrict__ fb,
    unsigned short* __restrict__ ehi, unsigned short* __restrict__ elo) {
  const int i = blockIdx.x * 256 + threadIdx.x;
  const float4* src = (const float4*)(emb + (size_t)i * D);
  float v[16];
  float4 a0 = src[0], a1 = src[1], a2 = src[2], a3 = src[3];
  v[0]=a0.x; v[1]=a0.y; v[2]=a0.z; v[3]=a0.w;
  v[4]=a1.x; v[5]=a1.y; v[6]=a1.z; v[7]=a1.w;
  v[8]=a2.x; v[9]=a2.y; v[10]=a2.z; v[11]=a2.w;
  v[12]=a3.x; v[13]=a3.y; v[14]=a3.z; v[15]=a3.w;

  float s = v[0] * v[0];
  unsigned short hi[16], lo[16];
#pragma unroll
  for (int k = 0; k < 16; ++k) {
    if (k) s = fmaf(v[k], v[k], s);
    hi[k] = f2bf(v[k]);
    lo[k] = f2bf(v[k] - bf2f(hi[k]));
  }
  sq[i] = s;
  {
    bf16x8* dh = (bf16x8*)(ehi + (size_t)i * 16);
    bf16x8* dl = (bf16x8*)(elo + (size_t)i * 16);
    dh[0] = *(bf16x8*)&hi[0]; dh[1] = *(bf16x8*)&hi[8];
    dl[0] = *(bf16x8*)&lo[0]; dl[1] = *(bf16x8*)&lo[8];
  }
  const int f = FAM_LUT[idx[i] & 63];
  fa[i] = (f >= 0) ? (float)f : -1.0f;  /* i-side: None = -1 */
  fb[i] = (f >= 0) ? (float)f : -2.0f;  /* j-side: None = -2 (None != None) */
}

__global__ __launch_bounds__(512, 8) void pair_kernel(
    const unsigned short* __restrict__ ehi, const unsigned short* __restrict__ elo,
    const float* __restrict__ sq,
    const float* __restrict__ fa, const float* __restrict__ fb,
    float* __restrict__ pt, float* __restrict__ ps) {
  /* triangular fold: grid (65,32) -> every block a live upper-tri 128x128 tile */
  const int u = blockIdx.y, bx = blockIdx.x;
  int it, jt;
  if (bx < NT - u) { it = u;          jt = u + bx; }
  else             { it = NT - 1 - u; jt = bx - 1; }

  /* B tile staged in MFMA fragment-linear order: [mj][half][lr] x 16B chunks */
  __shared__ __align__(16) unsigned short BH[2048];  /* 4KB */
  __shared__ __align__(16) unsigned short BL[2048];  /* 4KB */
  __shared__ float2 SFJ[TILE];                       /* x = sq_j, y = famB_j */
  __shared__ float rT[8], rS[8];

  const int t  = threadIdx.x;
  const int w  = t >> 6;          /* wave 0..7: i-strip w */
  const int l  = t & 63;
  const int lr = l & 15;          /* fragment row/col index */
  const int g  = l >> 4;          /* k-slice group 0..3 */
  const int half = g & 1;         /* dims 0-7 vs 8-15 */

  /* A fragment (pack [hi | lo] along K=32) + i-side scalars, from global/L2 */
  const unsigned short* asrc = (g < 2) ? ehi : elo;
  const int arow = it * TILE + w * 16 + lr;
  const bf16x8 afrag = *(const bf16x8*)(asrc + (size_t)arow * 16 + half * 8);
  float sqi[4], fai[4];
#pragma unroll
  for (int r = 0; r < 4; ++r) {
    const int irow = it * TILE + w * 16 + g * 4 + r;   /* C/D row = g*4+r */
    sqi[r] = sq[irow];
    fai[r] = fa[irow];
  }

  /* stage j-tile: 512 threads x one 16B chunk (waves 0-3: BH, 4-7: BL) */
  {
    const int c   = t & 255;
    const int mjs = c >> 5, hs = (c >> 4) & 1, lrs = c & 15;
    const int grow = jt * TILE + mjs * 16 + lrs;
    const unsigned short* src = (t < 256) ? ehi : elo;
    unsigned short*       dst = (t < 256) ? BH  : BL;
    *(bf16x8*)(dst + c * 8) = *(const bf16x8*)(src + (size_t)grow * 16 + hs * 8);
    if (t < TILE) SFJ[t] = make_float2(sq[jt * TILE + t], fb[jt * TILE + t]);
  }
  __syncthreads();

  const int bofs = (half * 16 + lr) * 8;   /* ushort offset within an mj-group */
  float accT = 0.0f, accS = 0.0f;
#pragma unroll 2
  for (int mj = 0; mj < 8; ++mj) {
    const bf16x8 bhi = *(const bf16x8*)(BH + mj * 256 + bofs);
    const bf16x8 blo = *(const bf16x8*)(BL + mj * 256 + bofs);
    const float2 sfj = SFJ[mj * 16 + lr];            /* C/D col = lr */
    /* B = lo replicated along K gives (hi_a+lo_a)*lo_b; then + (hi_a+lo_a)*hi_b */
    f32x4 acc = {0.0f, 0.0f, 0.0f, 0.0f};
    acc = __builtin_amdgcn_mfma_f32_16x16x32_bf16(afrag, blo, acc, 0, 0, 0);
    acc = __builtin_amdgcn_mfma_f32_16x16x32_bf16(afrag, bhi, acc, 0, 0, 0);
#pragma unroll
    for (int r = 0; r < 4; ++r) {
      float d2 = fmaf(-2.0f, acc[r], sqi[r] + sfj.x);
      d2 = fmaxf(d2, 0.0f);
      const float dist = SQRTF(d2);
      accT += dist;
      accS += (fai[r] == sfj.y) ? dist : 0.0f;
    }
  }

  /* block reduction (fp32 partials ~1e5, fine) */
#pragma unroll
  for (int off = 32; off > 0; off >>= 1) {
    accT += __shfl_down(accT, off);
    accS += __shfl_down(accS, off);
  }
  if (l == 0) { rT[w] = accT; rS[w] = accS; }
  __syncthreads();
  if (t == 0) {
    float sT = 0.0f, sS = 0.0f;
#pragma unroll
    for (int k = 0; k < 8; ++k) { sT += rT[k]; sS += rS[k]; }
    const float wgt = (it == jt) ? 1.0f : 2.0f;
    const int bid = blockIdx.y * gridDim.x + blockIdx.x;
    pt[bid] = wgt * sT;
    ps[bid] = wgt * sS;
  }
}

__global__ __launch_bounds__(1024) void final_kernel(
    const float* __restrict__ pt, const float* __restrict__ ps,
    const int* __restrict__ idx, float* __restrict__ out) {
  const int t = threadIdx.x;
  __shared__ int hist[8];
  __shared__ double rTd[16], rSd[16];
  if (t < 8) hist[t] = 0;
  __syncthreads();
  for (int k = t; k < N_ROWS; k += 1024) {
    const int f = FAM_LUT[idx[k] & 63];
    if (f >= 0) atomicAdd(&hist[f], 1);
  }

  double sT = 0.0, sS = 0.0;
  for (int k = t; k < NBLK; k += 1024) { sT += (double)pt[k]; sS += (double)ps[k]; }
#pragma unroll
  for (int off = 32; off > 0; off >>= 1) {
    sT += __shfl_down(sT, off);
    sS += __shfl_down(sS, off);
  }
  if ((t & 63) == 0) { rTd[t >> 6] = sT; rSd[t >> 6] = sS; }
  __syncthreads();
  if (t == 0) {
    double tot = 0.0, sam = 0.0;
#pragma unroll
    for (int k = 0; k < 16; ++k) { tot += rTd[k]; sam += rSd[k]; }
    double same_sum = 0.0;
    for (int f = 0; f < 6; ++f) { const double c = (double)hist[f]; same_sum += c * c; }
    const double total  = (double)N_ROWS * (double)N_ROWS;
    const double same_d = sam / (same_sum + 1e-10);
    const double diff_d = (tot - sam) / (total - same_sum + 1e-10);
    double loss = same_d - 0.5 * diff_d + 1.0;
    out[0] = (float)(loss > 0.0 ? loss : 0.0);
  }
}

extern "C" void kernel_launch(void* const* d_in, const int* in_sizes, int n_in,
                              void* d_out, int out_size, void* d_ws, size_t ws_size,
                              hipStream_t stream) {
  const float* emb = (const float*)d_in[0];
  const int*   idx = (const int*)d_in[1];
  char* ws = (char*)d_ws;
  float*          pt  = (float*)(ws + OFF_PT);
  float*          ps  = (float*)(ws + OFF_PS);
  float*          sqv = (float*)(ws + OFF_SQ);
  float*          fav = (float*)(ws + OFF_FA);
  float*          fbv = (float*)(ws + OFF_FB);
  unsigned short* ehi = (unsigned short*)(ws + OFF_EHI);
  unsigned short* elo = (unsigned short*)(ws + OFF_ELO);

  prep_kernel<<<dim3(N_ROWS / 256), dim3(256), 0, stream>>>(emb, idx, sqv, fav, fbv, ehi, elo);
  pair_kernel<<<dim3(NT + 1, NT / 2), dim3(512), 0, stream>>>(ehi, elo, sqv, fav, fbv, pt, ps);
  final_kernel<<<dim3(1), dim3(1024), 0, stream>>>(pt, ps, idx, (float*)d_out);
}